// Round 16
// baseline (175.449 us; speedup 1.0000x reference)
//
#include <hip/hip_runtime.h>

#define ODIM 128          // OUT_DIM
#define BROWS 128         // rows per bucket
#define NBMAX 512         // max buckets (N/128 = 391 for N=50000)
#define TILE 4096         // edges per partition tile (57KB LDS, 2 blocks/CU)
#define CMASK 0x1FFFFu    // low 17 bits of meta = col
#define HISTB 1024        // hist blocks in fused hist+conv kernel
#define CONVB 512         // conv blocks in fused hist+conv kernel
#define CBSH 13           // col-block shift: 8192-node (2MB) windows
#define BINS (BROWS * 8)  // pass-2 bins: row*8 + colblock

typedef unsigned u32;

__device__ inline unsigned f2bf(float x) {  // fp32 -> bf16 bits, RNE
  unsigned u = __float_as_uint(x);
  return (u + 0x7fffu + ((u >> 16) & 1u)) >> 16;
}

// ---- fused: bucket histogram (blocks < HISTB) + W->bf16 convert (rest) ----

__global__ __launch_bounds__(256) void hist_conv(
    const int* __restrict__ xr, int nx, const int* __restrict__ ar, int na,
    int* __restrict__ ghX, int* __restrict__ ghA,
    const float2* __restrict__ W2, u32* __restrict__ Wbf, int wwords) {
  __shared__ int lh[2 * NBMAX];
  if ((int)blockIdx.x >= HISTB) {
    int i = (blockIdx.x - HISTB) * 256 + threadIdx.x;
    int stride = CONVB * 256;
    for (; i < wwords; i += stride) {
      float2 w = W2[i];
      Wbf[i] = f2bf(w.x) | (f2bf(w.y) << 16);
    }
    return;
  }
  for (int i = threadIdx.x; i < 2 * NBMAX; i += 256) lh[i] = 0;
  __syncthreads();
  int total = nx + na;
  for (int i = blockIdx.x * 256 + threadIdx.x; i < total; i += HISTB * 256) {
    if (i < nx) atomicAdd(&lh[xr[i] >> 7], 1);
    else        atomicAdd(&lh[NBMAX + (ar[i - nx] >> 7)], 1);
  }
  __syncthreads();
  for (int b = threadIdx.x; b < NBMAX; b += 256) {
    if (lh[b])         atomicAdd(&ghX[b], lh[b]);
    if (lh[NBMAX + b]) atomicAdd(&ghA[b], lh[NBMAX + b]);
  }
}

// ---------------- bucket scan (block 0: X, block 1: A) ----------------

__global__ __launch_bounds__(NBMAX) void scan_buckets(
    int* __restrict__ ghX, int* __restrict__ baseX, int* __restrict__ curX,
    int* __restrict__ ghA, int* __restrict__ baseA, int* __restrict__ curA,
    int nb) {
  int* gh   = blockIdx.x ? ghA   : ghX;
  int* base = blockIdx.x ? baseA : baseX;
  int* cur  = blockIdx.x ? curA  : curX;
  __shared__ int s[NBMAX];
  int tid = threadIdx.x;
  int v = (tid < nb) ? gh[tid] : 0;
  s[tid] = v;
  __syncthreads();
  for (int off = 1; off < NBMAX; off <<= 1) {
    int t = (tid >= off) ? s[tid - off] : 0;
    __syncthreads();
    s[tid] += t;
    __syncthreads();
  }
  int excl = s[tid] - v;
  if (tid < nb) { base[tid] = excl; cur[tid] = excl; }
  if (tid == NBMAX - 1) base[nb] = s[tid];
}

// ---- pass 1: tile counting-sort into buckets (X and A fused in one grid) ----

__global__ __launch_bounds__(256) void partition_both(
    const int* __restrict__ xr, const int* __restrict__ xc,
    const float* __restrict__ xv, int nx, int ntX,
    int* __restrict__ curX, uint2* __restrict__ outX,
    const int* __restrict__ ar, const int* __restrict__ ac,
    const float* __restrict__ av, int na,
    int* __restrict__ curA, uint2* __restrict__ outA) {
  __shared__ uint2 pay[TILE];            // 32KB packed (meta, val)
  __shared__ unsigned short bkt[TILE];   // 8KB
  __shared__ unsigned short perm[TILE];  // 8KB
  __shared__ int hist[NBMAX];
  __shared__ int scn[NBMAX];
  __shared__ int cur[NBMAX];
  __shared__ int gbase[NBMAX];
  __shared__ int part[256];

  const int* rows; const int* cols; const float* vals;
  int nnz; int* gcur; uint2* outbuf; int tile;
  if ((int)blockIdx.x < ntX) {
    rows = xr; cols = xc; vals = xv; nnz = nx; gcur = curX; outbuf = outX;
    tile = blockIdx.x;
  } else {
    rows = ar; cols = ac; vals = av; nnz = na; gcur = curA; outbuf = outA;
    tile = blockIdx.x - ntX;
  }

  int tid = threadIdx.x;
  int tbase = tile * TILE;
  int cnt = nnz - tbase; if (cnt > TILE) cnt = TILE;

  for (int b = tid; b < NBMAX; b += 256) hist[b] = 0;
  __syncthreads();

  for (int j = tid; j < cnt; j += 256) {
    int r = rows[tbase + j];
    int c = cols[tbase + j];
    float v = vals[tbase + j];
    unsigned b = (unsigned)r >> 7;
    bkt[j] = (unsigned short)b;
    pay[j] = make_uint2(((unsigned)(r & 127) << 17) | (unsigned)c, __float_as_uint(v));
    atomicAdd(&hist[b], 1);
  }
  __syncthreads();

  int h0 = hist[2 * tid], h1 = hist[2 * tid + 1];
  int psum = h0 + h1;
  part[tid] = psum;
  __syncthreads();
  for (int off = 1; off < 256; off <<= 1) {
    int t = (tid >= off) ? part[tid - off] : 0;
    __syncthreads();
    part[tid] += t;
    __syncthreads();
  }
  int excl = part[tid] - psum;
  scn[2 * tid] = excl;     scn[2 * tid + 1] = excl + h0;
  cur[2 * tid] = excl;     cur[2 * tid + 1] = excl + h0;
  __syncthreads();

  for (int j = tid; j < cnt; j += 256) {
    int pos = atomicAdd(&cur[bkt[j]], 1);
    perm[pos] = (unsigned short)j;
  }
  for (int b = tid; b < NBMAX; b += 256) {
    int c = hist[b];
    if (c) gbase[b] = atomicAdd(&gcur[b], c);
  }
  __syncthreads();

  for (int p = tid; p < cnt; p += 256) {
    int j = perm[p];
    int b = bkt[j];
    outbuf[gbase[b] + (p - scn[b])] = pay[j];
  }
}

// ---- pass 2: per-bucket sort by (row, col-block) + rowptr (X and A fused) ----
// Key = (row&127)*8 + (col>>CBSH): rows grouped exactly as before, and within
// each row edges are grouped into 2MB col-windows. All waves sweep col-blocks
// in the same order -> smaller instantaneous L2 working set during pull.

__global__ __launch_bounds__(256) void bucket_sort_both(
    int nbX,
    const int* __restrict__ baseX, const uint2* __restrict__ binX,
    uint2* __restrict__ boutX, int* __restrict__ rpX,
    const int* __restrict__ baseA, const uint2* __restrict__ binA,
    uint2* __restrict__ boutA, int* __restrict__ rpA, int N) {
  __shared__ int hist[BINS];      // 4KB
  __shared__ int binstart[BINS];  // 4KB
  __shared__ int part[256];
  const int* base; const uint2* bufin; uint2* bufout; int* rowptr; int b;
  if ((int)blockIdx.x < nbX) {
    base = baseX; bufin = binX; bufout = boutX; rowptr = rpX; b = blockIdx.x;
  } else {
    base = baseA; bufin = binA; bufout = boutA; rowptr = rpA; b = blockIdx.x - nbX;
  }
  int tid = threadIdx.x;
  int e0 = base[b], ecnt = base[b + 1] - e0;

  for (int i = tid; i < BINS; i += 256) hist[i] = 0;
  __syncthreads();
  for (int j = tid; j < ecnt; j += 256) {
    unsigned m = bufin[e0 + j].x;
    atomicAdd(&hist[(m >> 17) * 8 + ((m & CMASK) >> CBSH)], 1);
  }
  __syncthreads();

  // exclusive scan over BINS=1024 bins: thread t owns bins 4t..4t+3
  int h[4]; int s = 0;
#pragma unroll
  for (int k = 0; k < 4; ++k) { h[k] = hist[4 * tid + k]; s += h[k]; }
  part[tid] = s;
  __syncthreads();
  for (int off = 1; off < 256; off <<= 1) {
    int t = (tid >= off) ? part[tid - off] : 0;
    __syncthreads();
    part[tid] += t;
    __syncthreads();
  }
  int run = part[tid] - s;
#pragma unroll
  for (int k = 0; k < 4; ++k) { binstart[4 * tid + k] = run; run += h[k]; }
  __syncthreads();

  // rowptr: row r starts at its first bin (r*8)
  if (tid < BROWS) {
    int node = b * BROWS + tid;
    if (node <= N) rowptr[node] = e0 + binstart[tid * 8];
  }
  __syncthreads();

  // scatter (binstart doubles as cursor after rowptr reads are done)
  for (int j = tid; j < ecnt; j += 256) {
    uint2 e = bufin[e0 + j];
    unsigned m = e.x;
    int pos = atomicAdd(&binstart[(m >> 17) * 8 + ((m & CMASK) >> CBSH)], 1);
    bufout[e0 + pos] = e;
  }
}

// ---------------- pulls (wave per row, register accumulate, 8-deep) ---------
// Table word l of a row = bf16(dim 2l) | bf16(dim 2l+1)<<16.

__global__ __launch_bounds__(256) void pull_x(
    const int* __restrict__ rowptr, const uint2* __restrict__ cv,
    const u32* __restrict__ Wbf, unsigned* __restrict__ xw, int nrows) {
  int lane = threadIdx.x & 63;
  int r = blockIdx.x * 4 + (threadIdx.x >> 6);
  if (r >= nrows) return;
  int e = rowptr[r], end = rowptr[r + 1];
  float acc0[8], acc1[8];
#pragma unroll
  for (int u = 0; u < 8; ++u) { acc0[u] = 0.f; acc1[u] = 0.f; }
  for (; e + 7 < end; e += 8) {
    uint2 ed[8]; unsigned xg[8];
#pragma unroll
    for (int u = 0; u < 8; ++u) ed[u] = cv[e + u];
#pragma unroll
    for (int u = 0; u < 8; ++u)
      xg[u] = Wbf[(size_t)(ed[u].x & CMASK) * 64 + lane];
#pragma unroll
    for (int u = 0; u < 8; ++u) {
      float v = __uint_as_float(ed[u].y);
      acc0[u] += v * __uint_as_float(xg[u] << 16);
      acc1[u] += v * __uint_as_float(xg[u] & 0xffff0000u);
    }
  }
  for (; e + 1 < end; e += 2) {
    uint2 ea = cv[e], eb = cv[e + 1];
    unsigned ua = Wbf[(size_t)(ea.x & CMASK) * 64 + lane];
    unsigned ub = Wbf[(size_t)(eb.x & CMASK) * 64 + lane];
    float va = __uint_as_float(ea.y), vb = __uint_as_float(eb.y);
    acc0[0] += va * __uint_as_float(ua << 16);
    acc1[0] += va * __uint_as_float(ua & 0xffff0000u);
    acc0[1] += vb * __uint_as_float(ub << 16);
    acc1[1] += vb * __uint_as_float(ub & 0xffff0000u);
  }
  if (e < end) {
    uint2 ea = cv[e];
    unsigned ua = Wbf[(size_t)(ea.x & CMASK) * 64 + lane];
    float va = __uint_as_float(ea.y);
    acc0[2] += va * __uint_as_float(ua << 16);
    acc1[2] += va * __uint_as_float(ua & 0xffff0000u);
  }
  float o0 = ((acc0[0] + acc0[1]) + (acc0[2] + acc0[3])) +
             ((acc0[4] + acc0[5]) + (acc0[6] + acc0[7]));
  float o1 = ((acc1[0] + acc1[1]) + (acc1[2] + acc1[3])) +
             ((acc1[4] + acc1[5]) + (acc1[6] + acc1[7]));
  xw[(size_t)r * 64 + lane] = f2bf(o0) | (f2bf(o1) << 16);
}

__global__ __launch_bounds__(256) void pull_a(
    const int* __restrict__ rowptr, const uint2* __restrict__ cv,
    const unsigned* __restrict__ xw, float2* __restrict__ out, int nrows) {
  int lane = threadIdx.x & 63;
  int r = blockIdx.x * 4 + (threadIdx.x >> 6);
  if (r >= nrows) return;
  int e = rowptr[r], end = rowptr[r + 1];
  float acc0[8], acc1[8];
#pragma unroll
  for (int u = 0; u < 8; ++u) { acc0[u] = 0.f; acc1[u] = 0.f; }
  for (; e + 7 < end; e += 8) {
    uint2 ed[8]; unsigned xg[8];
#pragma unroll
    for (int u = 0; u < 8; ++u) ed[u] = cv[e + u];
#pragma unroll
    for (int u = 0; u < 8; ++u)
      xg[u] = xw[(size_t)(ed[u].x & CMASK) * 64 + lane];
#pragma unroll
    for (int u = 0; u < 8; ++u) {
      float v = __uint_as_float(ed[u].y);
      acc0[u] += v * __uint_as_float(xg[u] << 16);
      acc1[u] += v * __uint_as_float(xg[u] & 0xffff0000u);
    }
  }
  for (; e + 1 < end; e += 2) {
    uint2 ea = cv[e], eb = cv[e + 1];
    unsigned ua = xw[(size_t)(ea.x & CMASK) * 64 + lane];
    unsigned ub = xw[(size_t)(eb.x & CMASK) * 64 + lane];
    float va = __uint_as_float(ea.y), vb = __uint_as_float(eb.y);
    acc0[0] += va * __uint_as_float(ua << 16);
    acc1[0] += va * __uint_as_float(ua & 0xffff0000u);
    acc0[1] += vb * __uint_as_float(ub << 16);
    acc1[1] += vb * __uint_as_float(ub & 0xffff0000u);
  }
  if (e < end) {
    uint2 ea = cv[e];
    unsigned ua = xw[(size_t)(ea.x & CMASK) * 64 + lane];
    float va = __uint_as_float(ea.y);
    acc0[2] += va * __uint_as_float(ua << 16);
    acc1[2] += va * __uint_as_float(ua & 0xffff0000u);
  }
  float o0 = ((acc0[0] + acc0[1]) + (acc0[2] + acc0[3])) +
             ((acc0[4] + acc0[5]) + (acc0[6] + acc0[7]));
  float o1 = ((acc1[0] + acc1[1]) + (acc1[2] + acc1[3])) +
             ((acc1[4] + acc1[5]) + (acc1[6] + acc1[7]));
  out[(size_t)r * 64 + lane] = make_float2(fmaxf(o0, 0.f), fmaxf(o1, 0.f));
}

// ---------------- fallback (atomic push) ----------------

__global__ __launch_bounds__(256) void spmm_scatter(
    const int* __restrict__ rows, const int* __restrict__ cols,
    const float* __restrict__ vals, const float* __restrict__ B,
    float* __restrict__ out, int nnz) {
  int e = blockIdx.x * 2 + (threadIdx.x >> 7);
  int d = threadIdx.x & (ODIM - 1);
  if (e >= nnz) return;
  atomicAdd(&out[(size_t)rows[e] * ODIM + d],
            vals[e] * B[(size_t)cols[e] * ODIM + d]);
}

__global__ __launch_bounds__(256) void relu_inplace(float* __restrict__ p, long n4) {
  long i = (long)blockIdx.x * blockDim.x + threadIdx.x;
  long stride = (long)gridDim.x * blockDim.x;
  float4* p4 = (float4*)p;
  for (long j = i; j < n4; j += stride) {
    float4 v = p4[j];
    v.x = fmaxf(v.x, 0.f); v.y = fmaxf(v.y, 0.f);
    v.z = fmaxf(v.z, 0.f); v.w = fmaxf(v.w, 0.f);
    p4[j] = v;
  }
}

extern "C" void kernel_launch(void* const* d_in, const int* in_sizes, int n_in,
                              void* d_out, int out_size, void* d_ws, size_t ws_size,
                              hipStream_t stream) {
  const int*   x_rows   = (const int*)d_in[0];
  const int*   x_cols   = (const int*)d_in[1];
  const float* x_vals   = (const float*)d_in[2];
  const int*   adj_rows = (const int*)d_in[3];
  const int*   adj_cols = (const int*)d_in[4];
  const float* adj_vals = (const float*)d_in[5];
  const float* W        = (const float*)d_in[6];

  const int nnz_x   = in_sizes[0];
  const int nnz_adj = in_sizes[3];
  const int wlen    = in_sizes[6];              // IN_DIM * ODIM
  const int N       = out_size / ODIM;          // 50000
  const int NB      = (N + BROWS - 1) / BROWS;  // 391
  const int ntX     = (nnz_x + TILE - 1) / TILE;
  const int ntA     = (nnz_adj + TILE - 1) / TILE;
  const int wwords  = wlen / 2;                 // packed bf16 words

  float* out = (float*)d_out;

  // Common control block
  char* p = (char*)d_ws;
  int* ghX   = (int*)p;  p += NBMAX * sizeof(int);
  int* ghA   = (int*)p;  p += NBMAX * sizeof(int);        // adjacent: one memset
  int* baseX = (int*)p;  p += (NBMAX + 1) * sizeof(int);
  int* baseA = (int*)p;  p += (NBMAX + 1) * sizeof(int);
  int* curX  = (int*)p;  p += NBMAX * sizeof(int);
  int* curA  = (int*)p;  p += NBMAX * sizeof(int);
  int* rpX   = (int*)p;  p += (size_t)(N + 1) * sizeof(int);
  int* rpA   = (int*)p;  p += (size_t)(N + 1) * sizeof(int);
  p = (char*)(((uintptr_t)p + 255) & ~(uintptr_t)255);
  u32* Wbf   = (u32*)p;  p += (size_t)wwords * sizeof(u32);
  p = (char*)(((uintptr_t)p + 255) & ~(uintptr_t)255);
  char* bufs = p;

  const size_t xw_bytes = (size_t)N * 64 * sizeof(u32);

  // --- Fused layout: separate ping buffers for X and A (one partition launch).
  // xw aliases bufPX..bufPA (dead after bucket_sort_both).
  {
    char* q = bufs;
    uint2* bufPX = (uint2*)q; q += (size_t)nnz_x * sizeof(uint2);
    uint2* bufPA = (uint2*)q; q += (size_t)nnz_adj * sizeof(uint2);
    uint2* bufSX = (uint2*)q; q += (size_t)nnz_x * sizeof(uint2);
    uint2* bufSA = (uint2*)q; q += (size_t)nnz_adj * sizeof(uint2);
    size_t need = (size_t)(q - (char*)d_ws);
    bool xw_fits = xw_bytes <= ((size_t)nnz_x + nnz_adj) * sizeof(uint2);
    if (ws_size >= need && NB <= NBMAX && xw_fits) {
      u32* xw = (u32*)bufPX;
      (void)hipMemsetAsync(ghX, 0, 2 * NBMAX * sizeof(int), stream);
      hist_conv<<<HISTB + CONVB, 256, 0, stream>>>(
          x_rows, nnz_x, adj_rows, nnz_adj, ghX, ghA,
          (const float2*)W, Wbf, wwords);
      scan_buckets<<<2, NBMAX, 0, stream>>>(ghX, baseX, curX, ghA, baseA, curA, NB);
      partition_both<<<ntX + ntA, 256, 0, stream>>>(
          x_rows, x_cols, x_vals, nnz_x, ntX, curX, bufPX,
          adj_rows, adj_cols, adj_vals, nnz_adj, curA, bufPA);
      bucket_sort_both<<<2 * NB, 256, 0, stream>>>(
          NB, baseX, bufPX, bufSX, rpX, baseA, bufPA, bufSA, rpA, N);
      pull_x<<<(N + 3) / 4, 256, 0, stream>>>(rpX, bufSX, Wbf, xw, N);
      pull_a<<<(N + 3) / 4, 256, 0, stream>>>(rpA, bufSA, xw, (float2*)out, N);
      return;
    }
  }

  // --- Sequential layout (shared ping buffer) if ws smaller.
  {
    size_t bufP_elems = (size_t)(nnz_x > nnz_adj ? nnz_x : nnz_adj);
    if (bufP_elems * sizeof(uint2) < xw_bytes)
      bufP_elems = (xw_bytes + sizeof(uint2) - 1) / sizeof(uint2);
    char* q = bufs;
    uint2* bufP  = (uint2*)q; q += bufP_elems * sizeof(uint2);
    uint2* bufSX = (uint2*)q; q += (size_t)nnz_x * sizeof(uint2);
    uint2* bufSA = (uint2*)q; q += (size_t)nnz_adj * sizeof(uint2);
    size_t need = (size_t)(q - (char*)d_ws);
    if (ws_size >= need && NB <= NBMAX) {
      u32* xw = (u32*)bufP;
      (void)hipMemsetAsync(ghX, 0, 2 * NBMAX * sizeof(int), stream);
      hist_conv<<<HISTB + CONVB, 256, 0, stream>>>(
          x_rows, nnz_x, adj_rows, nnz_adj, ghX, ghA,
          (const float2*)W, Wbf, wwords);
      scan_buckets<<<2, NBMAX, 0, stream>>>(ghX, baseX, curX, ghA, baseA, curA, NB);
      partition_both<<<ntX, 256, 0, stream>>>(
          x_rows, x_cols, x_vals, nnz_x, ntX, curX, bufP,
          adj_rows, adj_cols, adj_vals, nnz_adj, curA, bufP);
      bucket_sort_both<<<NB, 256, 0, stream>>>(
          NB, baseX, bufP, bufSX, rpX, baseA, bufP, bufSA, rpA, N);
      partition_both<<<ntA, 256, 0, stream>>>(
          x_rows, x_cols, x_vals, nnz_x, 0, curX, bufP,
          adj_rows, adj_cols, adj_vals, nnz_adj, curA, bufP);
      bucket_sort_both<<<NB, 256, 0, stream>>>(
          0, baseX, bufP, bufSX, rpX, baseA, bufP, bufSA, rpA, N);
      pull_x<<<(N + 3) / 4, 256, 0, stream>>>(rpX, bufSX, Wbf, xw, N);
      pull_a<<<(N + 3) / 4, 256, 0, stream>>>(rpA, bufSA, xw, (float2*)out, N);
      return;
    }
  }

  // --- Last resort: atomic push (needs only N*ODIM floats).
  {
    float* xwf = (float*)d_ws;
    const size_t out_bytes = (size_t)out_size * sizeof(float);
    (void)hipMemsetAsync(xwf, 0, out_bytes, stream);
    (void)hipMemsetAsync(out, 0, out_bytes, stream);
    spmm_scatter<<<(nnz_x + 1) / 2, 256, 0, stream>>>(x_rows, x_cols, x_vals, W, xwf, nnz_x);
    spmm_scatter<<<(nnz_adj + 1) / 2, 256, 0, stream>>>(adj_rows, adj_cols, adj_vals, xwf, out, nnz_adj);
    relu_inplace<<<2048, 256, 0, stream>>>(out, (long)out_size / 4);
  }
}

// Round 17
// 172.645 us; speedup vs baseline: 1.0162x; 1.0162x over previous
//
#include <hip/hip_runtime.h>

#define ODIM 128          // OUT_DIM
#define BROWS 128         // rows per bucket
#define NBMAX 512         // max buckets (N/128 = 391 for N=50000)
#define TILE 4096         // edges per partition tile (57KB LDS, 2 blocks/CU, 84B runs)
#define CMASK 0x1FFFFu    // low 17 bits of meta = col
#define HISTB 1024        // hist blocks in fused hist+conv kernel
#define CONVB 512         // conv blocks in fused hist+conv kernel

typedef unsigned u32;

__device__ inline unsigned f2bf(float x) {  // fp32 -> bf16 bits, RNE
  unsigned u = __float_as_uint(x);
  return (u + 0x7fffu + ((u >> 16) & 1u)) >> 16;
}

// ---- fused: bucket histogram (blocks < HISTB) + W->bf16 convert (rest) ----

__global__ __launch_bounds__(256) void hist_conv(
    const int* __restrict__ xr, int nx, const int* __restrict__ ar, int na,
    int* __restrict__ ghX, int* __restrict__ ghA,
    const float2* __restrict__ W2, u32* __restrict__ Wbf, int wwords) {
  __shared__ int lh[2 * NBMAX];
  if ((int)blockIdx.x >= HISTB) {
    int i = (blockIdx.x - HISTB) * 256 + threadIdx.x;
    int stride = CONVB * 256;
    for (; i < wwords; i += stride) {
      float2 w = W2[i];
      Wbf[i] = f2bf(w.x) | (f2bf(w.y) << 16);
    }
    return;
  }
  for (int i = threadIdx.x; i < 2 * NBMAX; i += 256) lh[i] = 0;
  __syncthreads();
  int total = nx + na;
  for (int i = blockIdx.x * 256 + threadIdx.x; i < total; i += HISTB * 256) {
    if (i < nx) atomicAdd(&lh[xr[i] >> 7], 1);
    else        atomicAdd(&lh[NBMAX + (ar[i - nx] >> 7)], 1);
  }
  __syncthreads();
  for (int b = threadIdx.x; b < NBMAX; b += 256) {
    if (lh[b])         atomicAdd(&ghX[b], lh[b]);
    if (lh[NBMAX + b]) atomicAdd(&ghA[b], lh[NBMAX + b]);
  }
}

// ---------------- bucket scan (block 0: X, block 1: A) ----------------

__global__ __launch_bounds__(NBMAX) void scan_buckets(
    int* __restrict__ ghX, int* __restrict__ baseX, int* __restrict__ curX,
    int* __restrict__ ghA, int* __restrict__ baseA, int* __restrict__ curA,
    int nb) {
  int* gh   = blockIdx.x ? ghA   : ghX;
  int* base = blockIdx.x ? baseA : baseX;
  int* cur  = blockIdx.x ? curA  : curX;
  __shared__ int s[NBMAX];
  int tid = threadIdx.x;
  int v = (tid < nb) ? gh[tid] : 0;
  s[tid] = v;
  __syncthreads();
  for (int off = 1; off < NBMAX; off <<= 1) {
    int t = (tid >= off) ? s[tid - off] : 0;
    __syncthreads();
    s[tid] += t;
    __syncthreads();
  }
  int excl = s[tid] - v;
  if (tid < nb) { base[tid] = excl; cur[tid] = excl; }
  if (tid == NBMAX - 1) base[nb] = s[tid];
}

// ---- pass 1: tile counting-sort into buckets (X and A fused in one grid) ----

__global__ __launch_bounds__(256) void partition_both(
    const int* __restrict__ xr, const int* __restrict__ xc,
    const float* __restrict__ xv, int nx, int ntX,
    int* __restrict__ curX, uint2* __restrict__ outX,
    const int* __restrict__ ar, const int* __restrict__ ac,
    const float* __restrict__ av, int na,
    int* __restrict__ curA, uint2* __restrict__ outA) {
  __shared__ uint2 pay[TILE];            // 32KB packed (meta, val)
  __shared__ unsigned short bkt[TILE];   // 8KB
  __shared__ unsigned short perm[TILE];  // 8KB
  __shared__ int hist[NBMAX];
  __shared__ int scn[NBMAX];
  __shared__ int cur[NBMAX];
  __shared__ int gbase[NBMAX];
  __shared__ int part[256];

  const int* rows; const int* cols; const float* vals;
  int nnz; int* gcur; uint2* outbuf; int tile;
  if ((int)blockIdx.x < ntX) {
    rows = xr; cols = xc; vals = xv; nnz = nx; gcur = curX; outbuf = outX;
    tile = blockIdx.x;
  } else {
    rows = ar; cols = ac; vals = av; nnz = na; gcur = curA; outbuf = outA;
    tile = blockIdx.x - ntX;
  }

  int tid = threadIdx.x;
  int tbase = tile * TILE;
  int cnt = nnz - tbase; if (cnt > TILE) cnt = TILE;

  for (int b = tid; b < NBMAX; b += 256) hist[b] = 0;
  __syncthreads();

  for (int j = tid; j < cnt; j += 256) {
    int r = rows[tbase + j];
    int c = cols[tbase + j];
    float v = vals[tbase + j];
    unsigned b = (unsigned)r >> 7;
    bkt[j] = (unsigned short)b;
    pay[j] = make_uint2(((unsigned)(r & 127) << 17) | (unsigned)c, __float_as_uint(v));
    atomicAdd(&hist[b], 1);
  }
  __syncthreads();

  int h0 = hist[2 * tid], h1 = hist[2 * tid + 1];
  int psum = h0 + h1;
  part[tid] = psum;
  __syncthreads();
  for (int off = 1; off < 256; off <<= 1) {
    int t = (tid >= off) ? part[tid - off] : 0;
    __syncthreads();
    part[tid] += t;
    __syncthreads();
  }
  int excl = part[tid] - psum;
  scn[2 * tid] = excl;     scn[2 * tid + 1] = excl + h0;
  cur[2 * tid] = excl;     cur[2 * tid + 1] = excl + h0;
  __syncthreads();

  for (int j = tid; j < cnt; j += 256) {
    int pos = atomicAdd(&cur[bkt[j]], 1);
    perm[pos] = (unsigned short)j;
  }
  for (int b = tid; b < NBMAX; b += 256) {
    int c = hist[b];
    if (c) gbase[b] = atomicAdd(&gcur[b], c);
  }
  __syncthreads();

  for (int p = tid; p < cnt; p += 256) {
    int j = perm[p];
    int b = bkt[j];
    outbuf[gbase[b] + (p - scn[b])] = pay[j];
  }
}

// ---- pass 2: per-bucket exact row sort + rowptr (X and A fused) ----

__global__ __launch_bounds__(256) void bucket_sort_both(
    int nbX,
    const int* __restrict__ baseX, const uint2* __restrict__ binX,
    uint2* __restrict__ boutX, int* __restrict__ rpX,
    const int* __restrict__ baseA, const uint2* __restrict__ binA,
    uint2* __restrict__ boutA, int* __restrict__ rpA, int N) {
  __shared__ int hist[BROWS], scn[BROWS], cur[BROWS];
  const int* base; const uint2* bufin; uint2* bufout; int* rowptr; int b;
  if ((int)blockIdx.x < nbX) {
    base = baseX; bufin = binX; bufout = boutX; rowptr = rpX; b = blockIdx.x;
  } else {
    base = baseA; bufin = binA; bufout = boutA; rowptr = rpA; b = blockIdx.x - nbX;
  }
  int tid = threadIdx.x;
  int e0 = base[b], ecnt = base[b + 1] - e0;

  if (tid < BROWS) hist[tid] = 0;
  __syncthreads();
  for (int j = tid; j < ecnt; j += 256)
    atomicAdd(&hist[bufin[e0 + j].x >> 17], 1);
  __syncthreads();

  int v = (tid < BROWS) ? hist[tid] : 0;
  if (tid < BROWS) scn[tid] = v;
  __syncthreads();
  for (int off = 1; off < BROWS; off <<= 1) {
    int t = (tid < BROWS && tid >= off) ? scn[tid - off] : 0;
    __syncthreads();
    if (tid < BROWS) scn[tid] += t;
    __syncthreads();
  }
  if (tid < BROWS) {
    int excl = scn[tid] - v;
    cur[tid] = excl;
    int node = b * BROWS + tid;
    if (node <= N) rowptr[node] = e0 + excl;
  }
  __syncthreads();

  for (int j = tid; j < ecnt; j += 256) {
    uint2 e = bufin[e0 + j];
    int pos = atomicAdd(&cur[e.x >> 17], 1);
    bufout[e0 + pos] = e;
  }
}

// ---------------- pulls (wave per row, register accumulate, 8-deep) ---------
// Table word l of a row = bf16(dim 2l) | bf16(dim 2l+1)<<16.

__global__ __launch_bounds__(256) void pull_x(
    const int* __restrict__ rowptr, const uint2* __restrict__ cv,
    const u32* __restrict__ Wbf, unsigned* __restrict__ xw, int nrows) {
  int lane = threadIdx.x & 63;
  int r = blockIdx.x * 4 + (threadIdx.x >> 6);
  if (r >= nrows) return;
  int e = rowptr[r], end = rowptr[r + 1];
  float acc0[8], acc1[8];
#pragma unroll
  for (int u = 0; u < 8; ++u) { acc0[u] = 0.f; acc1[u] = 0.f; }
  for (; e + 7 < end; e += 8) {
    uint2 ed[8]; unsigned xg[8];
#pragma unroll
    for (int u = 0; u < 8; ++u) ed[u] = cv[e + u];
#pragma unroll
    for (int u = 0; u < 8; ++u)
      xg[u] = Wbf[(size_t)(ed[u].x & CMASK) * 64 + lane];
#pragma unroll
    for (int u = 0; u < 8; ++u) {
      float v = __uint_as_float(ed[u].y);
      acc0[u] += v * __uint_as_float(xg[u] << 16);
      acc1[u] += v * __uint_as_float(xg[u] & 0xffff0000u);
    }
  }
  for (; e + 1 < end; e += 2) {
    uint2 ea = cv[e], eb = cv[e + 1];
    unsigned ua = Wbf[(size_t)(ea.x & CMASK) * 64 + lane];
    unsigned ub = Wbf[(size_t)(eb.x & CMASK) * 64 + lane];
    float va = __uint_as_float(ea.y), vb = __uint_as_float(eb.y);
    acc0[0] += va * __uint_as_float(ua << 16);
    acc1[0] += va * __uint_as_float(ua & 0xffff0000u);
    acc0[1] += vb * __uint_as_float(ub << 16);
    acc1[1] += vb * __uint_as_float(ub & 0xffff0000u);
  }
  if (e < end) {
    uint2 ea = cv[e];
    unsigned ua = Wbf[(size_t)(ea.x & CMASK) * 64 + lane];
    float va = __uint_as_float(ea.y);
    acc0[2] += va * __uint_as_float(ua << 16);
    acc1[2] += va * __uint_as_float(ua & 0xffff0000u);
  }
  float o0 = ((acc0[0] + acc0[1]) + (acc0[2] + acc0[3])) +
             ((acc0[4] + acc0[5]) + (acc0[6] + acc0[7]));
  float o1 = ((acc1[0] + acc1[1]) + (acc1[2] + acc1[3])) +
             ((acc1[4] + acc1[5]) + (acc1[6] + acc1[7]));
  xw[(size_t)r * 64 + lane] = f2bf(o0) | (f2bf(o1) << 16);
}

__global__ __launch_bounds__(256) void pull_a(
    const int* __restrict__ rowptr, const uint2* __restrict__ cv,
    const unsigned* __restrict__ xw, float2* __restrict__ out, int nrows) {
  int lane = threadIdx.x & 63;
  int r = blockIdx.x * 4 + (threadIdx.x >> 6);
  if (r >= nrows) return;
  int e = rowptr[r], end = rowptr[r + 1];
  float acc0[8], acc1[8];
#pragma unroll
  for (int u = 0; u < 8; ++u) { acc0[u] = 0.f; acc1[u] = 0.f; }
  for (; e + 7 < end; e += 8) {
    uint2 ed[8]; unsigned xg[8];
#pragma unroll
    for (int u = 0; u < 8; ++u) ed[u] = cv[e + u];
#pragma unroll
    for (int u = 0; u < 8; ++u)
      xg[u] = xw[(size_t)(ed[u].x & CMASK) * 64 + lane];
#pragma unroll
    for (int u = 0; u < 8; ++u) {
      float v = __uint_as_float(ed[u].y);
      acc0[u] += v * __uint_as_float(xg[u] << 16);
      acc1[u] += v * __uint_as_float(xg[u] & 0xffff0000u);
    }
  }
  for (; e + 1 < end; e += 2) {
    uint2 ea = cv[e], eb = cv[e + 1];
    unsigned ua = xw[(size_t)(ea.x & CMASK) * 64 + lane];
    unsigned ub = xw[(size_t)(eb.x & CMASK) * 64 + lane];
    float va = __uint_as_float(ea.y), vb = __uint_as_float(eb.y);
    acc0[0] += va * __uint_as_float(ua << 16);
    acc1[0] += va * __uint_as_float(ua & 0xffff0000u);
    acc0[1] += vb * __uint_as_float(ub << 16);
    acc1[1] += vb * __uint_as_float(ub & 0xffff0000u);
  }
  if (e < end) {
    uint2 ea = cv[e];
    unsigned ua = xw[(size_t)(ea.x & CMASK) * 64 + lane];
    float va = __uint_as_float(ea.y);
    acc0[2] += va * __uint_as_float(ua << 16);
    acc1[2] += va * __uint_as_float(ua & 0xffff0000u);
  }
  float o0 = ((acc0[0] + acc0[1]) + (acc0[2] + acc0[3])) +
             ((acc0[4] + acc0[5]) + (acc0[6] + acc0[7]));
  float o1 = ((acc1[0] + acc1[1]) + (acc1[2] + acc1[3])) +
             ((acc1[4] + acc1[5]) + (acc1[6] + acc1[7]));
  out[(size_t)r * 64 + lane] = make_float2(fmaxf(o0, 0.f), fmaxf(o1, 0.f));
}

// ---------------- fallback (atomic push) ----------------

__global__ __launch_bounds__(256) void spmm_scatter(
    const int* __restrict__ rows, const int* __restrict__ cols,
    const float* __restrict__ vals, const float* __restrict__ B,
    float* __restrict__ out, int nnz) {
  int e = blockIdx.x * 2 + (threadIdx.x >> 7);
  int d = threadIdx.x & (ODIM - 1);
  if (e >= nnz) return;
  atomicAdd(&out[(size_t)rows[e] * ODIM + d],
            vals[e] * B[(size_t)cols[e] * ODIM + d]);
}

__global__ __launch_bounds__(256) void relu_inplace(float* __restrict__ p, long n4) {
  long i = (long)blockIdx.x * blockDim.x + threadIdx.x;
  long stride = (long)gridDim.x * blockDim.x;
  float4* p4 = (float4*)p;
  for (long j = i; j < n4; j += stride) {
    float4 v = p4[j];
    v.x = fmaxf(v.x, 0.f); v.y = fmaxf(v.y, 0.f);
    v.z = fmaxf(v.z, 0.f); v.w = fmaxf(v.w, 0.f);
    p4[j] = v;
  }
}

extern "C" void kernel_launch(void* const* d_in, const int* in_sizes, int n_in,
                              void* d_out, int out_size, void* d_ws, size_t ws_size,
                              hipStream_t stream) {
  const int*   x_rows   = (const int*)d_in[0];
  const int*   x_cols   = (const int*)d_in[1];
  const float* x_vals   = (const float*)d_in[2];
  const int*   adj_rows = (const int*)d_in[3];
  const int*   adj_cols = (const int*)d_in[4];
  const float* adj_vals = (const float*)d_in[5];
  const float* W        = (const float*)d_in[6];

  const int nnz_x   = in_sizes[0];
  const int nnz_adj = in_sizes[3];
  const int wlen    = in_sizes[6];              // IN_DIM * ODIM
  const int N       = out_size / ODIM;          // 50000
  const int NB      = (N + BROWS - 1) / BROWS;  // 391
  const int ntX     = (nnz_x + TILE - 1) / TILE;
  const int ntA     = (nnz_adj + TILE - 1) / TILE;
  const int wwords  = wlen / 2;                 // packed bf16 words

  float* out = (float*)d_out;

  // Common control block
  char* p = (char*)d_ws;
  int* ghX   = (int*)p;  p += NBMAX * sizeof(int);
  int* ghA   = (int*)p;  p += NBMAX * sizeof(int);        // adjacent: one memset
  int* baseX = (int*)p;  p += (NBMAX + 1) * sizeof(int);
  int* baseA = (int*)p;  p += (NBMAX + 1) * sizeof(int);
  int* curX  = (int*)p;  p += NBMAX * sizeof(int);
  int* curA  = (int*)p;  p += NBMAX * sizeof(int);
  int* rpX   = (int*)p;  p += (size_t)(N + 1) * sizeof(int);
  int* rpA   = (int*)p;  p += (size_t)(N + 1) * sizeof(int);
  p = (char*)(((uintptr_t)p + 255) & ~(uintptr_t)255);
  u32* Wbf   = (u32*)p;  p += (size_t)wwords * sizeof(u32);
  p = (char*)(((uintptr_t)p + 255) & ~(uintptr_t)255);
  char* bufs = p;

  const size_t xw_bytes = (size_t)N * 64 * sizeof(u32);

  // --- Fused layout: separate ping buffers for X and A (one partition launch).
  // xw aliases bufPX..bufPA (dead after bucket_sort_both).
  {
    char* q = bufs;
    uint2* bufPX = (uint2*)q; q += (size_t)nnz_x * sizeof(uint2);
    uint2* bufPA = (uint2*)q; q += (size_t)nnz_adj * sizeof(uint2);
    uint2* bufSX = (uint2*)q; q += (size_t)nnz_x * sizeof(uint2);
    uint2* bufSA = (uint2*)q; q += (size_t)nnz_adj * sizeof(uint2);
    size_t need = (size_t)(q - (char*)d_ws);
    bool xw_fits = xw_bytes <= ((size_t)nnz_x + nnz_adj) * sizeof(uint2);
    if (ws_size >= need && NB <= NBMAX && xw_fits) {
      u32* xw = (u32*)bufPX;
      (void)hipMemsetAsync(ghX, 0, 2 * NBMAX * sizeof(int), stream);
      hist_conv<<<HISTB + CONVB, 256, 0, stream>>>(
          x_rows, nnz_x, adj_rows, nnz_adj, ghX, ghA,
          (const float2*)W, Wbf, wwords);
      scan_buckets<<<2, NBMAX, 0, stream>>>(ghX, baseX, curX, ghA, baseA, curA, NB);
      partition_both<<<ntX + ntA, 256, 0, stream>>>(
          x_rows, x_cols, x_vals, nnz_x, ntX, curX, bufPX,
          adj_rows, adj_cols, adj_vals, nnz_adj, curA, bufPA);
      bucket_sort_both<<<2 * NB, 256, 0, stream>>>(
          NB, baseX, bufPX, bufSX, rpX, baseA, bufPA, bufSA, rpA, N);
      pull_x<<<(N + 3) / 4, 256, 0, stream>>>(rpX, bufSX, Wbf, xw, N);
      pull_a<<<(N + 3) / 4, 256, 0, stream>>>(rpA, bufSA, xw, (float2*)out, N);
      return;
    }
  }

  // --- Sequential layout (shared ping buffer) if ws smaller.
  {
    size_t bufP_elems = (size_t)(nnz_x > nnz_adj ? nnz_x : nnz_adj);
    if (bufP_elems * sizeof(uint2) < xw_bytes)
      bufP_elems = (xw_bytes + sizeof(uint2) - 1) / sizeof(uint2);
    char* q = bufs;
    uint2* bufP  = (uint2*)q; q += bufP_elems * sizeof(uint2);
    uint2* bufSX = (uint2*)q; q += (size_t)nnz_x * sizeof(uint2);
    uint2* bufSA = (uint2*)q; q += (size_t)nnz_adj * sizeof(uint2);
    size_t need = (size_t)(q - (char*)d_ws);
    if (ws_size >= need && NB <= NBMAX) {
      u32* xw = (u32*)bufP;
      (void)hipMemsetAsync(ghX, 0, 2 * NBMAX * sizeof(int), stream);
      hist_conv<<<HISTB + CONVB, 256, 0, stream>>>(
          x_rows, nnz_x, adj_rows, nnz_adj, ghX, ghA,
          (const float2*)W, Wbf, wwords);
      scan_buckets<<<2, NBMAX, 0, stream>>>(ghX, baseX, curX, ghA, baseA, curA, NB);
      partition_both<<<ntX, 256, 0, stream>>>(
          x_rows, x_cols, x_vals, nnz_x, ntX, curX, bufP,
          adj_rows, adj_cols, adj_vals, nnz_adj, curA, bufP);
      bucket_sort_both<<<NB, 256, 0, stream>>>(
          NB, baseX, bufP, bufSX, rpX, baseA, bufP, bufSA, rpA, N);
      partition_both<<<ntA, 256, 0, stream>>>(
          x_rows, x_cols, x_vals, nnz_x, 0, curX, bufP,
          adj_rows, adj_cols, adj_vals, nnz_adj, curA, bufP);
      bucket_sort_both<<<NB, 256, 0, stream>>>(
          0, baseX, bufP, bufSX, rpX, baseA, bufP, bufSA, rpA, N);
      pull_x<<<(N + 3) / 4, 256, 0, stream>>>(rpX, bufSX, Wbf, xw, N);
      pull_a<<<(N + 3) / 4, 256, 0, stream>>>(rpA, bufSA, xw, (float2*)out, N);
      return;
    }
  }

  // --- Last resort: atomic push (needs only N*ODIM floats).
  {
    float* xwf = (float*)d_ws;
    const size_t out_bytes = (size_t)out_size * sizeof(float);
    (void)hipMemsetAsync(xwf, 0, out_bytes, stream);
    (void)hipMemsetAsync(out, 0, out_bytes, stream);
    spmm_scatter<<<(nnz_x + 1) / 2, 256, 0, stream>>>(x_rows, x_cols, x_vals, W, xwf, nnz_x);
    spmm_scatter<<<(nnz_adj + 1) / 2, 256, 0, stream>>>(adj_rows, adj_cols, adj_vals, xwf, out, nnz_adj);
    relu_inplace<<<2048, 256, 0, stream>>>(out, (long)out_size / 4);
  }
}